// Round 4
// baseline (1320.720 us; speedup 1.0000x reference)
//
#include <hip/hip_runtime.h>
#include <hip/hip_cooperative_groups.h>

namespace cg = cooperative_groups;

#define SS 336
#define VV 8
#define DD 256
#define DKK 32
#define NTOK 5376            // B*V*S = B*S*V tokens
#define NTD (NTOK * DD)      // 1376256 elements per activation buffer
#define ATT_SCALE 0.17677669529663687f  // 1/sqrt(32)
#define LN_EPS 1e-5f

typedef _Float16 f16x8 __attribute__((ext_vector_type(8)));
typedef _Float16 f16x4v __attribute__((ext_vector_type(4)));
typedef __attribute__((ext_vector_type(4))) float f32x4;

__device__ inline _Float16 f2h(float f) { return (_Float16)f; }

// ---------------- weight prep: MFMA B-fragment order -----------------------
// WT2 offset(z, ntile, kb, lane, j) = z*65536 + (ntile*8+kb)*512 + lane*8 + j
// holds W_z[k][n] with n = ntile*16 + (lane&15), k = kb*32 + (lane>>4)*8 + j.
__global__ __launch_bounds__(256) void k_prep_w(
    const float* __restrict__ Wq, const float* __restrict__ Wk,
    const float* __restrict__ Wv, const float* __restrict__ Wo,
    _Float16* __restrict__ WT2) {
  int z = blockIdx.y;
  const float* W = (z == 0) ? Wq : (z == 1) ? Wk : (z == 2) ? Wv : Wo;
  int o = blockIdx.x * 256 + threadIdx.x;   // 0..65535
  int blk = o >> 9;                          // ntile*8 + kb
  int idx = o & 511;
  int lane = idx >> 3, j = idx & 7;
  int nt = blk >> 3, kb = blk & 7;
  int lcol = lane & 15, quad = lane >> 4;
  int n = nt * 16 + lcol;
  int k = kb * 32 + quad * 8 + j;
  WT2[(size_t)z * 65536 + o] = f2h(W[k * 256 + n]);
}

// ---------------- embed ----------------------------------------------------
__global__ __launch_bounds__(256) void k_embed(
    const float* __restrict__ x, const float* __restrict__ ew,
    const float* __restrict__ eb, float* __restrict__ E,
    _Float16* __restrict__ E16) {
  int token = blockIdx.x;            // (b*V+v)*S + s
  int n = token / SS, s = token - n * SS;
  int b = n >> 3, v = n & 7;
  float xv = x[(b * SS + s) * VV + v];
  int d = threadIdx.x;
  float val = fmaf(xv, ew[d], eb[d]);
  E[token * DD + d] = val;
  E16[token * DD + d] = f2h(val);
}

// ---------------- QKV GEMM (pre-loop only): H_z = A @ Wz + bz --------------
__global__ __launch_bounds__(256) void k_gemm_qkv(
    const _Float16* __restrict__ A16, const _Float16* __restrict__ WT2,
    const float* __restrict__ c0, const float* __restrict__ c1,
    const float* __restrict__ c2,
    _Float16* __restrict__ H0, _Float16* __restrict__ H1,
    _Float16* __restrict__ H2) {
  int z = blockIdx.z;
  const float* bias = (z == 0) ? c0 : (z == 1) ? c1 : c2;
  _Float16* H       = (z == 0) ? H0 : (z == 1) ? H1 : H2;
  int m0 = blockIdx.x * 64;
  int tid = threadIdx.x;
  int wave = tid >> 6, lane = tid & 63;
  int wm = wave >> 1, wn = wave & 1;
  int quad = lane >> 4, lcol = lane & 15;
  int ntb = blockIdx.y * 8 + wn * 4;    // base n-tile for this wave

  __shared__ _Float16 As[64 * 264];     // 33 KB, stride-264 (2-way banks)

  for (int c = tid; c < 2048; c += 256) {
    int row = c >> 5, seg = c & 31;
    *(f16x8*)&As[row * 264 + seg * 8] =
        *(const f16x8*)&A16[(size_t)(m0 + row) * 256 + seg * 8];
  }
  __syncthreads();

  f32x4 acc[2][4] = {};

  for (int kb = 0; kb < 8; ++kb) {
    int k0 = kb * 32;
    f16x8 af[2];
#pragma unroll
    for (int mt = 0; mt < 2; ++mt)
      af[mt] = *(const f16x8*)&As[(wm * 32 + mt * 16 + lcol) * 264 + k0 + quad * 8];
#pragma unroll
    for (int nt = 0; nt < 4; ++nt) {
      f16x8 bfr = *(const f16x8*)&WT2[(size_t)z * 65536 +
                                      ((ntb + nt) * 8 + kb) * 512 + lane * 8];
#pragma unroll
      for (int mt = 0; mt < 2; ++mt)
        acc[mt][nt] = __builtin_amdgcn_mfma_f32_16x16x32_f16(
            af[mt], bfr, acc[mt][nt], 0, 0, 0);
    }
  }

  float bsv[4];
#pragma unroll
  for (int nt = 0; nt < 4; ++nt) bsv[nt] = bias[(ntb + nt) * 16 + lcol];
#pragma unroll
  for (int mt = 0; mt < 2; ++mt) {
#pragma unroll
    for (int i = 0; i < 4; ++i) {
      int r = m0 + wm * 32 + mt * 16 + quad * 4 + i;
#pragma unroll
      for (int nt = 0; nt < 4; ++nt) {
        int c = (ntb + nt) * 16 + lcol;
        H[(size_t)r * 256 + c] = f2h(acc[mt][nt][i] + bsv[nt]);
      }
    }
  }
}

// ---------------- fused 10-iteration loop (cooperative) ---------------------
// 256 blocks x 512 thr. Per iter: attn phase (all blocks; = old grid (2,8,16))
// -> grid.sync -> mega_var phase (blocks 0..167) -> grid.sync.
// Replaces 20 dispatches with 1 (19 grid syncs). LDS: overlaid union, 99968 B.
#define KSTR 36
#define VTSTR 344
#define PSTR 72

__global__ __launch_bounds__(512) void k_loop(
    _Float16* __restrict__ Q16, _Float16* __restrict__ K16,
    _Float16* __restrict__ V16, _Float16* __restrict__ AO16,
    const _Float16* __restrict__ WT2,
    const float* __restrict__ bq, const float* __restrict__ bk,
    const float* __restrict__ bv, const float* __restrict__ bo,
    const float* __restrict__ g1, const float* __restrict__ c1,
    const float* __restrict__ gn, const float* __restrict__ bn,
    float* __restrict__ Etime) {
  cg::grid_group grid = cg::this_grid();

  __shared__ __align__(16) char SMRAW[99968];

  int bid = blockIdx.x;
  int tid = threadIdx.x;
  int wave = tid >> 6, lane = tid & 63;
  int quad = lane >> 4, lcol = lane & 15;

  const _Float16* WoF = WT2 + (size_t)3 * 65536;   // Wo frag block

  for (int it = 0; it < 10; ++it) {
    // ================= attn phase =================
    {
      _Float16* Ks  = (_Float16*)SMRAW;                    // 24192 B
      _Float16* Vt  = (_Float16*)(SMRAW + 24192);          // 22048 B
      _Float16* PsB = (_Float16*)(SMRAW + 46240);          // 18432 B

      int qg = bid & 1, h = (bid >> 1) & 7, n = bid >> 4;
      const size_t base = (size_t)(n * SS) * DD + h * DKK;

      for (int c = tid; c < 1344; c += 512) {
        int row = c >> 2, part = c & 3;
        f16x8 kv = *(const f16x8*)&K16[base + (size_t)row * DD + part * 8];
        f16x4v klo = __builtin_shufflevector(kv, kv, 0, 1, 2, 3);
        f16x4v khi = __builtin_shufflevector(kv, kv, 4, 5, 6, 7);
        *(f16x4v*)&Ks[row * KSTR + part * 8] = klo;
        *(f16x4v*)&Ks[row * KSTR + part * 8 + 4] = khi;
        f16x8 vv = *(const f16x8*)&V16[base + (size_t)row * DD + part * 8];
#pragma unroll
        for (int j = 0; j < 8; ++j) Vt[(part * 8 + j) * VTSTR + row] = vv[j];
      }
      for (int c = tid; c < 272; c += 512) {
        if (c < 256) {
          int d = c >> 3, col = 336 + (c & 7);
          Vt[d * VTSTR + col] = (_Float16)0.f;
        } else {
          Vt[32 * VTSTR + (c - 256)] = (_Float16)0.f;
        }
      }
      __syncthreads();

      _Float16* P = PsB + wave * (16 * PSTR);
      const f16x8 onesv = {(_Float16)1.f, (_Float16)1.f, (_Float16)1.f, (_Float16)1.f,
                           (_Float16)1.f, (_Float16)1.f, (_Float16)1.f, (_Float16)1.f};
      const f32x4 z4 = {0.f, 0.f, 0.f, 0.f};

      int qt0 = qg ? 11 : 0;
      int qtend = qg ? 21 : 11;
      for (int qtile = qt0 + wave; qtile < qtend; qtile += 8) {
        int qb = qtile * 16;

        f16x8 qf = *(const f16x8*)&Q16[base + (size_t)(qb + lcol) * DD + quad * 8];
        f32x4 accA = {0.f, 0.f, 0.f, 0.f};
        f32x4 accB = {0.f, 0.f, 0.f, 0.f};
        f32x4 lacc = {0.f, 0.f, 0.f, 0.f};
        float m_[4] = {-1e30f, -1e30f, -1e30f, -1e30f};

        // 336 = 5*64 + 16: T=0..4 full 64-key blocks, T=5 tail (16 keys)
        for (int T = 0; T < 6; ++T) {
          int k0 = T * 64;
          bool full = (T < 5);
          f32x4 s[4];
          {
            const _Float16* kp = &Ks[(k0 + lcol) * KSTR + quad * 8];
            f16x4v a0 = *(const f16x4v*)kp;
            f16x4v b0 = *(const f16x4v*)(kp + 4);
            f16x8 kf = __builtin_shufflevector(a0, b0, 0, 1, 2, 3, 4, 5, 6, 7);
            s[0] = __builtin_amdgcn_mfma_f32_16x16x32_f16(qf, kf, z4, 0, 0, 0);
          }
          if (full) {
#pragma unroll
            for (int u = 1; u < 4; ++u) {
              const _Float16* kp = &Ks[(k0 + u * 16 + lcol) * KSTR + quad * 8];
              f16x4v a0 = *(const f16x4v*)kp;
              f16x4v b0 = *(const f16x4v*)(kp + 4);
              f16x8 kf = __builtin_shufflevector(a0, b0, 0, 1, 2, 3, 4, 5, 6, 7);
              s[u] = __builtin_amdgcn_mfma_f32_16x16x32_f16(qf, kf, z4, 0, 0, 0);
            }
          } else {
            s[1] = z4; s[2] = z4; s[3] = z4;
          }
          float sc[4][4], p[4][4], corr[4];
#pragma unroll
          for (int u = 0; u < 4; ++u)
#pragma unroll
            for (int i = 0; i < 4; ++i)
              sc[u][i] = (u == 0 || full) ? s[u][i] * ATT_SCALE : -1e30f;
#pragma unroll
          for (int i = 0; i < 4; ++i) {
            float t2 = fmaxf(fmaxf(sc[0][i], sc[1][i]), fmaxf(sc[2][i], sc[3][i]));
            t2 = fmaxf(t2, __shfl_xor(t2, 1));
            t2 = fmaxf(t2, __shfl_xor(t2, 2));
            t2 = fmaxf(t2, __shfl_xor(t2, 4));
            t2 = fmaxf(t2, __shfl_xor(t2, 8));
            float nm = fmaxf(m_[i], t2);
            corr[i] = __expf(m_[i] - nm);
            m_[i] = nm;
#pragma unroll
            for (int u = 0; u < 4; ++u) p[u][i] = __expf(sc[u][i] - nm);
            accA[i] *= corr[i];
            accB[i] *= corr[i];
            lacc[i] *= corr[i];
          }
#pragma unroll
          for (int i = 0; i < 4; ++i)
#pragma unroll
            for (int u = 0; u < 4; ++u)
              P[(quad * 4 + i) * PSTR + u * 16 + lcol] = f2h(p[u][i]);
          f16x8 pf0 = *(const f16x8*)&P[lcol * PSTR + quad * 8];
          lacc = __builtin_amdgcn_mfma_f32_16x16x32_f16(pf0, onesv, lacc, 0, 0, 0);
          f16x8 va0 = *(const f16x8*)&Vt[lcol * VTSTR + k0 + quad * 8];
          f16x8 vb0 = *(const f16x8*)&Vt[(16 + lcol) * VTSTR + k0 + quad * 8];
          accA = __builtin_amdgcn_mfma_f32_16x16x32_f16(pf0, va0, accA, 0, 0, 0);
          accB = __builtin_amdgcn_mfma_f32_16x16x32_f16(pf0, vb0, accB, 0, 0, 0);
          if (full) {
            f16x8 pf1 = *(const f16x8*)&P[lcol * PSTR + 32 + quad * 8];
            lacc = __builtin_amdgcn_mfma_f32_16x16x32_f16(pf1, onesv, lacc, 0, 0, 0);
            f16x8 va1 = *(const f16x8*)&Vt[lcol * VTSTR + k0 + 32 + quad * 8];
            f16x8 vb1 = *(const f16x8*)&Vt[(16 + lcol) * VTSTR + k0 + 32 + quad * 8];
            accA = __builtin_amdgcn_mfma_f32_16x16x32_f16(pf1, va1, accA, 0, 0, 0);
            accB = __builtin_amdgcn_mfma_f32_16x16x32_f16(pf1, vb1, accB, 0, 0, 0);
          }
        }

#pragma unroll
        for (int i = 0; i < 4; ++i) {
          float inv = 1.f / lacc[i];
          P[(quad * 4 + i) * PSTR + lcol] = f2h(accA[i] * inv);
          P[(quad * 4 + i) * PSTR + 16 + lcol] = f2h(accB[i] * inv);
        }
        int row = lane >> 2, seg = lane & 3;
        f16x8 ov = *(const f16x8*)&P[row * PSTR + seg * 8];
        *(f16x8*)&AO16[base + (size_t)(qb + row) * DD + seg * 8] = ov;
      }
    }
    grid.sync();

    // ================= mega_var phase (blocks 0..167) =================
    if (bid < 168) {
      int* rmapS     = (int*)SMRAW;                    // 128 B
      _Float16* Af   = (_Float16*)(SMRAW + 128);       // 16896 B
      float* Cf      = (float*)(SMRAW + 17024);        // 33280 B
      _Float16* QKVs = (_Float16*)(SMRAW + 50304);     // 49664 B
      int doqkv = (it < 9) ? 1 : 0;

      if (tid < 32) {
        int r2 = bid * 32 + tid;
        int n_idx = r2 >> 3, v = r2 & 7;
        int b = n_idx / SS, s = n_idx - b * SS;
        rmapS[tid] = (b * VV + v) * SS + s;
      }
      __syncthreads();

      // stage AO rows (time layout, gathered) into Af
      {
        int row = tid >> 4, seg = tid & 15;
        const _Float16* src = AO16 + (size_t)rmapS[row] * DD + seg * 16;
        _Float16* dst = Af + row * 264 + seg * 16;
        *(f16x8*)(dst) = *(const f16x8*)(src);
        *(f16x8*)(dst + 8) = *(const f16x8*)(src + 8);
      }
      __syncthreads();

      // ---- time O-proj: Cf = Af @ Wo + bo + Etime(res) ----
      {
        f32x4 acc[2][2] = {};
        for (int kb = 0; kb < 8; ++kb) {
          int k0 = kb * 32;
          f16x8 af0 = *(const f16x8*)&Af[lcol * 264 + k0 + quad * 8];
          f16x8 af1 = *(const f16x8*)&Af[(16 + lcol) * 264 + k0 + quad * 8];
#pragma unroll
          for (int nt = 0; nt < 2; ++nt) {
            f16x8 bfr = *(const f16x8*)&WoF[((wave * 2 + nt) * 8 + kb) * 512 + lane * 8];
            acc[0][nt] = __builtin_amdgcn_mfma_f32_16x16x32_f16(af0, bfr, acc[0][nt], 0, 0, 0);
            acc[1][nt] = __builtin_amdgcn_mfma_f32_16x16x32_f16(af1, bfr, acc[1][nt], 0, 0, 0);
          }
        }
#pragma unroll
        for (int mt = 0; mt < 2; ++mt) {
#pragma unroll
          for (int i = 0; i < 4; ++i) {
            int row = mt * 16 + quad * 4 + i;
            size_t rb = (size_t)rmapS[row] * 256;
#pragma unroll
            for (int nt = 0; nt < 2; ++nt) {
              int col = (wave * 2 + nt) * 16 + lcol;
              Cf[row * 260 + col] = acc[mt][nt][i] + bo[col] + Etime[rb + col];
            }
          }
        }
      }
      __syncthreads();

      // ---- double LN (ln1 then norm); write Cf fp32 + Af f16 ----
      {
        int row = tid >> 4, c0 = (tid & 15) * 16;
        float v[16];
#pragma unroll
        for (int j = 0; j < 16; ++j) v[j] = Cf[row * 260 + c0 + j];
#pragma unroll
        for (int pass = 0; pass < 2; ++pass) {
          const float* gg = pass ? gn : g1;
          const float* bb = pass ? bn : c1;
          float s = 0.f, q = 0.f;
#pragma unroll
          for (int j = 0; j < 16; ++j) { s += v[j]; q = fmaf(v[j], v[j], q); }
          s += __shfl_xor(s, 1); q += __shfl_xor(q, 1);
          s += __shfl_xor(s, 2); q += __shfl_xor(q, 2);
          s += __shfl_xor(s, 4); q += __shfl_xor(q, 4);
          s += __shfl_xor(s, 8); q += __shfl_xor(q, 8);
          float mu = s * (1.0f / 256.0f);
          float rs = rsqrtf(q * (1.0f / 256.0f) - mu * mu + LN_EPS);
#pragma unroll
          for (int j = 0; j < 16; ++j)
            v[j] = fmaf((v[j] - mu) * rs, gg[c0 + j], bb[c0 + j]);
        }
#pragma unroll
        for (int j = 0; j < 16; ++j) Cf[row * 260 + c0 + j] = v[j];
#pragma unroll
        for (int j8 = 0; j8 < 2; ++j8) {
          f16x8 h;
#pragma unroll
          for (int jj = 0; jj < 8; ++jj) h[jj] = f2h(v[j8 * 8 + jj]);
          *(f16x8*)&Af[row * 264 + c0 + j8 * 8] = h;
        }
      }
      __syncthreads();

      // ---- var QKV: QKVs[32][768] = Af @ {Wq|Wk|Wv} + bias ----
      {
        f32x4 acc[2][6] = {};
        for (int kb = 0; kb < 8; ++kb) {
          int k0 = kb * 32;
          f16x8 af0 = *(const f16x8*)&Af[lcol * 264 + k0 + quad * 8];
          f16x8 af1 = *(const f16x8*)&Af[(16 + lcol) * 264 + k0 + quad * 8];
#pragma unroll
          for (int j = 0; j < 6; ++j) {
            int ntg = wave * 6 + j;                   // 0..47 == z*16 + ntile
            f16x8 bfr = *(const f16x8*)&WT2[(size_t)(ntg * 8 + kb) * 512 + lane * 8];
            acc[0][j] = __builtin_amdgcn_mfma_f32_16x16x32_f16(af0, bfr, acc[0][j], 0, 0, 0);
            acc[1][j] = __builtin_amdgcn_mfma_f32_16x16x32_f16(af1, bfr, acc[1][j], 0, 0, 0);
          }
        }
#pragma unroll
        for (int j = 0; j < 6; ++j) {
          int ntg = wave * 6 + j;
          int colb = ntg * 16;
          int z = colb >> 8, coln = (colb & 255) + lcol;
          const float* bz = (z == 0) ? bq : (z == 1) ? bk : bv;
          float bval = bz[coln];
#pragma unroll
          for (int mt = 0; mt < 2; ++mt) {
#pragma unroll
            for (int i = 0; i < 4; ++i)
              QKVs[(mt * 16 + quad * 4 + i) * 776 + colb + lcol] = f2h(acc[mt][j][i] + bval);
          }
        }
      }
      __syncthreads();

      // ---- var attention: all 512 thr; thread pairs split the 32 dims ----
      {
        int half = tid & 1, qi = (tid >> 1) & 7, h = (tid >> 4) & 7, ng = tid >> 7;
        int d0 = h * 32 + half * 16;
        const _Float16* Qp = &QKVs[(ng * 8 + qi) * 776 + d0];
        float qv[16];
#pragma unroll
        for (int j8 = 0; j8 < 2; ++j8) {
          f16x8 t = *(const f16x8*)(Qp + j8 * 8);
#pragma unroll
          for (int jj = 0; jj < 8; ++jj) qv[j8 * 8 + jj] = (float)t[jj];
        }
        float sc[8];
#pragma unroll
        for (int k = 0; k < 8; ++k) {
          const _Float16* Kp = &QKVs[(ng * 8 + k) * 776 + 256 + d0];
          float s = 0.f;
#pragma unroll
          for (int j8 = 0; j8 < 2; ++j8) {
            f16x8 t = *(const f16x8*)(Kp + j8 * 8);
#pragma unroll
            for (int jj = 0; jj < 8; ++jj) s = fmaf(qv[j8 * 8 + jj], (float)t[jj], s);
          }
          sc[k] = s;
        }
#pragma unroll
        for (int k = 0; k < 8; ++k)
          sc[k] = (sc[k] + __shfl_xor(sc[k], 1)) * ATT_SCALE;
        float mx = sc[0];
#pragma unroll
        for (int k = 1; k < 8; ++k) mx = fmaxf(mx, sc[k]);
        float ps = 0.f;
#pragma unroll
        for (int k = 0; k < 8; ++k) { sc[k] = __expf(sc[k] - mx); ps += sc[k]; }
        float inv = 1.f / ps;
        float ov[16];
#pragma unroll
        for (int j = 0; j < 16; ++j) ov[j] = 0.f;
#pragma unroll
        for (int k = 0; k < 8; ++k) {
          const _Float16* Vp = &QKVs[(ng * 8 + k) * 776 + 512 + d0];
          float p = sc[k];
#pragma unroll
          for (int j8 = 0; j8 < 2; ++j8) {
            f16x8 t = *(const f16x8*)(Vp + j8 * 8);
#pragma unroll
            for (int jj = 0; jj < 8; ++jj)
              ov[j8 * 8 + jj] = fmaf(p, (float)t[jj], ov[j8 * 8 + jj]);
          }
        }
        _Float16* Op = &Af[(ng * 8 + qi) * 264 + d0];
#pragma unroll
        for (int j8 = 0; j8 < 2; ++j8) {
          f16x8 hh;
#pragma unroll
          for (int jj = 0; jj < 8; ++jj) hh[jj] = f2h(ov[j8 * 8 + jj] * inv);
          *(f16x8*)(Op + j8 * 8) = hh;
        }
      }
      __syncthreads();

      // ---- var O-proj: Cf = Af @ Wo + bo + Cf(res x_var) ----
      {
        f32x4 acc[2][2] = {};
        for (int kb = 0; kb < 8; ++kb) {
          int k0 = kb * 32;
          f16x8 af0 = *(const f16x8*)&Af[lcol * 264 + k0 + quad * 8];
          f16x8 af1 = *(const f16x8*)&Af[(16 + lcol) * 264 + k0 + quad * 8];
#pragma unroll
          for (int nt = 0; nt < 2; ++nt) {
            f16x8 bfr = *(const f16x8*)&WoF[((wave * 2 + nt) * 8 + kb) * 512 + lane * 8];
            acc[0][nt] = __builtin_amdgcn_mfma_f32_16x16x32_f16(af0, bfr, acc[0][nt], 0, 0, 0);
            acc[1][nt] = __builtin_amdgcn_mfma_f32_16x16x32_f16(af1, bfr, acc[1][nt], 0, 0, 0);
          }
        }
#pragma unroll
        for (int mt = 0; mt < 2; ++mt) {
#pragma unroll
          for (int i = 0; i < 4; ++i) {
            int row = mt * 16 + quad * 4 + i;
#pragma unroll
            for (int nt = 0; nt < 2; ++nt) {
              int col = (wave * 2 + nt) * 16 + lcol;
              Cf[row * 260 + col] = acc[mt][nt][i] + bo[col] + Cf[row * 260 + col];
            }
          }
        }
      }
      __syncthreads();

      // ---- final LN1 + store Etime (f32) + Af (f16, feeds fused QKV) ----
      {
        int row = tid >> 4, c0 = (tid & 15) * 16;
        float v[16];
#pragma unroll
        for (int j = 0; j < 16; ++j) v[j] = Cf[row * 260 + c0 + j];
        float s = 0.f, q = 0.f;
#pragma unroll
        for (int j = 0; j < 16; ++j) { s += v[j]; q = fmaf(v[j], v[j], q); }
        s += __shfl_xor(s, 1); q += __shfl_xor(q, 1);
        s += __shfl_xor(s, 2); q += __shfl_xor(q, 2);
        s += __shfl_xor(s, 4); q += __shfl_xor(q, 4);
        s += __shfl_xor(s, 8); q += __shfl_xor(q, 8);
        float mu = s * (1.0f / 256.0f);
        float rs = rsqrtf(q * (1.0f / 256.0f) - mu * mu + LN_EPS);
#pragma unroll
        for (int j = 0; j < 16; ++j)
          v[j] = fmaf((v[j] - mu) * rs, g1[c0 + j], c1[c0 + j]);
        size_t rb = (size_t)rmapS[row] * 256 + c0;
#pragma unroll
        for (int j4 = 0; j4 < 4; ++j4) {
          float4 f4 = make_float4(v[j4 * 4], v[j4 * 4 + 1], v[j4 * 4 + 2], v[j4 * 4 + 3]);
          *(float4*)&Etime[rb + j4 * 4] = f4;
        }
#pragma unroll
        for (int j8 = 0; j8 < 2; ++j8) {
          f16x8 hh;
#pragma unroll
          for (int jj = 0; jj < 8; ++jj) hh[jj] = f2h(v[j8 * 8 + jj]);
          *(f16x8*)&Af[row * 264 + c0 + j8 * 8] = hh;
        }
      }
      __syncthreads();

      // ---- fused next-iteration time-stage QKV (skipped on last iter) ----
      if (doqkv) {
        f32x4 acc[2][6] = {};
        for (int kb = 0; kb < 8; ++kb) {
          int k0 = kb * 32;
          f16x8 af0 = *(const f16x8*)&Af[lcol * 264 + k0 + quad * 8];
          f16x8 af1 = *(const f16x8*)&Af[(16 + lcol) * 264 + k0 + quad * 8];
#pragma unroll
          for (int j = 0; j < 6; ++j) {
            int ntg = wave * 6 + j;                   // 0..47 == z*16 + ntile
            f16x8 bfr = *(const f16x8*)&WT2[(size_t)(ntg * 8 + kb) * 512 + lane * 8];
            acc[0][j] = __builtin_amdgcn_mfma_f32_16x16x32_f16(af0, bfr, acc[0][j], 0, 0, 0);
            acc[1][j] = __builtin_amdgcn_mfma_f32_16x16x32_f16(af1, bfr, acc[1][j], 0, 0, 0);
          }
        }
#pragma unroll
        for (int j = 0; j < 6; ++j) {
          int ntg = wave * 6 + j;
          int colb = ntg * 16;
          int z = colb >> 8, coln = (colb & 255) + lcol;
          const float* bz = (z == 0) ? bq : (z == 1) ? bk : bv;
          _Float16* Hd = (z == 0) ? Q16 : (z == 1) ? K16 : V16;
          float bval = bz[coln];
#pragma unroll
          for (int mt = 0; mt < 2; ++mt) {
#pragma unroll
            for (int i = 0; i < 4; ++i) {
              int row = mt * 16 + quad * 4 + i;
              Hd[(size_t)rmapS[row] * 256 + coln] = f2h(acc[mt][j][i] + bval);
            }
          }
        }
      }
    }
    if (it < 9) grid.sync();
  }
}

// ---------------- final projection -----------------------------------------
__global__ __launch_bounds__(192) void k_proj_partial(
    const float* __restrict__ E, const float* __restrict__ PW,
    float* __restrict__ Part) {
  int kc = blockIdx.x;
  int tid = threadIdx.x;
  int p4 = tid % 24, g = tid / 24;
  __shared__ float Es[16][128];
  __shared__ float sm[8][1536];
  for (int idx = tid; idx < 512; idx += 192) {
    int row = idx >> 5, kk4 = idx & 31;
    *(float4*)&Es[row][kk4 * 4] =
        *(const float4*)&E[(size_t)row * 86016 + kc * 128 + kk4 * 4];
  }
  __syncthreads();
  float4 acc[16];
#pragma unroll
  for (int i = 0; i < 16; ++i) acc[i] = make_float4(0.f, 0.f, 0.f, 0.f);
  for (int j = 0; j < 16; ++j) {
    int k = g * 16 + j;
    float4 w = *(const float4*)&PW[(size_t)(kc * 128 + k) * 96 + p4 * 4];
#pragma unroll
    for (int row = 0; row < 16; ++row) {
      float e = Es[row][k];
      acc[row].x = fmaf(e, w.x, acc[row].x);
      acc[row].y = fmaf(e, w.y, acc[row].y);
      acc[row].z = fmaf(e, w.z, acc[row].z);
      acc[row].w = fmaf(e, w.w, acc[row].w);
    }
  }
#pragma unroll
  for (int row = 0; row < 16; ++row)
    *(float4*)&sm[g][row * 96 + p4 * 4] = acc[row];
  __syncthreads();
  for (int o = tid; o < 1536; o += 192) {
    float s = 0.f;
#pragma unroll
    for (int g2 = 0; g2 < 8; ++g2) s += sm[g2][o];
    Part[(size_t)kc * 1536 + o] = s;
  }
}

// 96 blocks x 256 thr: block owns 16 j's; 16-way c-split per j, tree-reduce.
__global__ __launch_bounds__(256) void k_proj_reduce(
    const float* __restrict__ Part, const float* __restrict__ PB,
    float* __restrict__ out) {
  __shared__ float red[4][16];
  int tid = threadIdx.x;
  int j = (blockIdx.x << 4) | (tid & 15);   // 0..1535
  int cg = tid >> 4;                         // 0..15
  float s = 0.f;
#pragma unroll 7
  for (int i = 0; i < 42; ++i) {
    int c = cg * 42 + i;
    s += Part[(size_t)c * 1536 + j];
  }
  s += __shfl_xor(s, 16);
  s += __shfl_xor(s, 32);
  int wv = tid >> 6;
  if ((tid & 63) < 16) red[wv][tid & 15] = s;
  __syncthreads();
  if (tid < 16) {
    float t = red[0][tid] + red[1][tid] + red[2][tid] + red[3][tid];
    int jj = (blockIdx.x << 4) | tid;
    int row = jj / 96, p = jj - row * 96;
    int b = row >> 3, v = row & 7;
    out[b * 768 + p * 8 + v] = PB[p] + t;
  }
}

// ---------------- launch ---------------------------------------------------
extern "C" void kernel_launch(void* const* d_in, const int* in_sizes, int n_in,
                              void* d_out, int out_size, void* d_ws,
                              size_t ws_size, hipStream_t stream) {
  const float* x     = (const float*)d_in[0];
  const float* emb_w = (const float*)d_in[1];
  const float* emb_b = (const float*)d_in[2];
  const float* Wq = (const float*)d_in[3];
  const float* bq = (const float*)d_in[4];
  const float* Wk = (const float*)d_in[5];
  const float* bk = (const float*)d_in[6];
  const float* Wv = (const float*)d_in[7];
  const float* bv = (const float*)d_in[8];
  const float* Wo = (const float*)d_in[9];
  const float* bo = (const float*)d_in[10];
  const float* g1 = (const float*)d_in[11];
  const float* b1 = (const float*)d_in[12];
  const float* gn = (const float*)d_in[13];
  const float* bn = (const float*)d_in[14];
  const float* PW = (const float*)d_in[15];
  const float* PB = (const float*)d_in[16];
  float* out = (float*)d_out;

  float* ws = (float*)d_ws;
  float* Etime   = ws;                              // NTD f32
  _Float16* Et16 = (_Float16*)(ws + (size_t)NTD);   // NTD f16
  _Float16* Q16  = (_Float16*)(ws + (size_t)NTD + NTD / 2);
  _Float16* K16  = Q16 + (size_t)NTD;
  _Float16* V16  = K16 + (size_t)NTD;
  _Float16* AO16 = V16 + (size_t)NTD;
  _Float16* WT2  = AO16 + (size_t)NTD;              // 4*65536 f16 (frag order)
  float* Part    = (float*)(WT2 + 4 * 65536);       // 672*1536 f32

  k_prep_w<<<dim3(256, 4), 256, 0, stream>>>(Wq, Wk, Wv, Wo, WT2);
  k_embed<<<NTOK, 256, 0, stream>>>(x, emb_w, emb_b, Etime, Et16);
  k_gemm_qkv<<<dim3(84, 2, 3), 256, 0, stream>>>(
      Et16, WT2, bq, bk, bv, Q16, K16, V16);

  {
    void* args[] = {
      (void*)&Q16, (void*)&K16, (void*)&V16, (void*)&AO16, (void*)&WT2,
      (void*)&bq, (void*)&bk, (void*)&bv, (void*)&bo,
      (void*)&g1, (void*)&b1, (void*)&gn, (void*)&bn, (void*)&Etime
    };
    hipLaunchCooperativeKernel((void*)k_loop, dim3(256), dim3(512),
                               args, 0, stream);
  }

  k_proj_partial<<<672, 192, 0, stream>>>(Etime, PW, Part);
  k_proj_reduce<<<96, 256, 0, stream>>>(Part, PB, out);
}

// Round 5
// 587.734 us; speedup vs baseline: 2.2471x; 2.2471x over previous
//
#include <hip/hip_runtime.h>

#define SS 336
#define VV 8
#define DD 256
#define DKK 32
#define NTOK 5376            // B*V*S = B*S*V tokens
#define NTD (NTOK * DD)      // 1376256 elements per activation buffer
#define ATT_SCALE 0.17677669529663687f  // 1/sqrt(32)
#define LN_EPS 1e-5f

typedef _Float16 f16x8 __attribute__((ext_vector_type(8)));
typedef _Float16 f16x4v __attribute__((ext_vector_type(4)));
typedef __attribute__((ext_vector_type(4))) float f32x4;

__device__ inline _Float16 f2h(float f) { return (_Float16)f; }

// ---------------- weight prep: MFMA B-fragment order -----------------------
// WT2 offset(z, ntile, kb, lane, j) = z*65536 + (ntile*8+kb)*512 + lane*8 + j
// holds W_z[k][n] with n = ntile*16 + (lane&15), k = kb*32 + (lane>>4)*8 + j.
__global__ __launch_bounds__(256) void k_prep_w(
    const float* __restrict__ Wq, const float* __restrict__ Wk,
    const float* __restrict__ Wv, const float* __restrict__ Wo,
    _Float16* __restrict__ WT2) {
  int z = blockIdx.y;
  const float* W = (z == 0) ? Wq : (z == 1) ? Wk : (z == 2) ? Wv : Wo;
  int o = blockIdx.x * 256 + threadIdx.x;   // 0..65535
  int blk = o >> 9;                          // ntile*8 + kb
  int idx = o & 511;
  int lane = idx >> 3, j = idx & 7;
  int nt = blk >> 3, kb = blk & 7;
  int lcol = lane & 15, quad = lane >> 4;
  int n = nt * 16 + lcol;
  int k = kb * 32 + quad * 8 + j;
  WT2[(size_t)z * 65536 + o] = f2h(W[k * 256 + n]);
}

// ---------------- embed ----------------------------------------------------
__global__ __launch_bounds__(256) void k_embed(
    const float* __restrict__ x, const float* __restrict__ ew,
    const float* __restrict__ eb, float* __restrict__ E,
    _Float16* __restrict__ E16) {
  int token = blockIdx.x;            // (b*V+v)*S + s
  int n = token / SS, s = token - n * SS;
  int b = n >> 3, v = n & 7;
  float xv = x[(b * SS + s) * VV + v];
  int d = threadIdx.x;
  float val = fmaf(xv, ew[d], eb[d]);
  E[token * DD + d] = val;
  E16[token * DD + d] = f2h(val);
}

// ---------------- time attention + fused per-head QKV ----------------------
// grid (2, 8, 16) = 256 blocks x 512 thr (8 waves).
// Phase 1: per-head QKV mini-GEMM from Et16 (f2h of LN output): K,V full 336
// rows; Q only this block's qg half. Same WT2 frags + kb order + bias add as
// the old k_gemm_qkv -> bitwise identical Q/K/V, but never leaves LDS.
// Phase 2: flash attention (identical to R3 structure), Q from LDS.
#define KSTR 36
#define VTSTR 344
#define PSTR 72
#define QSTR 40
__global__ __launch_bounds__(512) void k_attn_time(
    const _Float16* __restrict__ Et16, const _Float16* __restrict__ WT2,
    const float* __restrict__ bq, const float* __restrict__ bk,
    const float* __restrict__ bv, _Float16* __restrict__ O16) {
  int qg = blockIdx.x, h = blockIdx.y, n = blockIdx.z;
  int tid = threadIdx.x;
  int wave = tid >> 6, lane = tid & 63;
  int quad = lane >> 4, lcol = lane & 15;

  // LDS layout (bytes):
  //   [0,24192)       Ks   336 x 36 f16
  //   [24192,46240)   Vt   (32*344+16) f16
  //   [46240,60320)   Qs   11 x 16 x 40 f16
  //   [60320,109472)  Wl   6 ot x 8 kb x 512 f16   (GEMM only)
  //   [109472,143264) Ach  64 x 264 f16            (GEMM only)
  //   Ps overlays Wl at 60320 (8 x 16 x 72 f16 = 18432 B, flash only)
  __shared__ __align__(16) char SMRAW[143264];
  _Float16* Ks  = (_Float16*)SMRAW;
  _Float16* Vt  = (_Float16*)(SMRAW + 24192);
  _Float16* Qs  = (_Float16*)(SMRAW + 46240);
  _Float16* Wl  = (_Float16*)(SMRAW + 60320);
  _Float16* Ach = (_Float16*)(SMRAW + 109472);
  _Float16* PsB = (_Float16*)(SMRAW + 60320);

  const size_t ebase = (size_t)(n * SS) * DD;   // this n's token rows
  const size_t base  = ebase + h * DKK;         // head slice for O-write
  int qt0 = qg ? 11 : 0;
  int qtend = qg ? 21 : 11;

  const f32x4 z4 = {0.f, 0.f, 0.f, 0.f};

  // ---- phase 1a: copy W slices (Wk|Wv|Wq, this head's 2 n-tiles each) ----
  // ot: 0=K0(z1,2h) 1=K1(z1,2h+1) 2=V0(z2,2h) 3=V1(z2,2h+1) 4=Q0(z0,2h) 5=Q1(z0,2h+1)
  {
    int h2 = h * 2;
    for (int c = tid; c < 3072; c += 512) {     // 3072 f16x8
      int ot = c >> 9, rest = c & 511;
      int z = (ot < 2) ? 1 : (ot < 4) ? 2 : 0;
      int nt = h2 + (ot & 1);
      *(f16x8*)&Wl[(ot << 12) + rest * 8] =
          *(const f16x8*)&WT2[(size_t)z * 65536 + nt * 4096 + rest * 8];
    }
    // zero Vt pads (cols 336..343 for all 32 d-rows, + 16-elem tail)
    for (int c = tid; c < 272; c += 512) {
      if (c < 256) {
        int d = c >> 3, col = 336 + (c & 7);
        Vt[d * VTSTR + col] = (_Float16)0.f;
      } else {
        Vt[32 * VTSTR + (c - 256)] = (_Float16)0.f;
      }
    }
  }

  // ---- phase 1b: QKV GEMM over 6 m-chunks (5x64 + 1x16 rows) ----
  for (int ck = 0; ck < 6; ++ck) {
    int m0c = ck * 64;
    int nmt = (ck < 5) ? 4 : 1;
    __syncthreads();   // protect Ach (and on ck=0: Wl writes) from readers
    for (int c = tid; c < nmt * 16 * 32; c += 512) {
      int row = c >> 5, seg = c & 31;
      *(f16x8*)&Ach[row * 264 + seg * 8] =
          *(const f16x8*)&Et16[ebase + (size_t)(m0c + row) * 256 + seg * 8];
    }
    __syncthreads();
    int nU = nmt * 6;
    for (int u = wave; u < nU; u += 8) {
      int mtl = u / 6, ot = u % 6;
      int gt = ck * 4 + mtl;
      if (ot >= 4 && (gt < qt0 || gt >= qtend)) continue;
      f32x4 acc = z4;
#pragma unroll
      for (int kb = 0; kb < 8; ++kb) {
        f16x8 af = *(const f16x8*)&Ach[(mtl * 16 + lcol) * 264 + kb * 32 + quad * 8];
        f16x8 wf = *(const f16x8*)&Wl[(ot << 12) + kb * 512 + lane * 8];
        acc = __builtin_amdgcn_mfma_f32_16x16x32_f16(af, wf, acc, 0, 0, 0);
      }
      int dlo = ((ot & 1) << 4) + lcol;                // 0..31 within head
      const float* bz = (ot < 2) ? bk : (ot < 4) ? bv : bq;
      float bval = bz[h * 32 + dlo];
      if (ot < 2) {          // K -> Ks[key][d]
#pragma unroll
        for (int i = 0; i < 4; ++i)
          Ks[(m0c + mtl * 16 + quad * 4 + i) * KSTR + dlo] = f2h(acc[i] + bval);
      } else if (ot < 4) {   // V -> Vt[d][key] (transposed)
#pragma unroll
        for (int i = 0; i < 4; ++i)
          Vt[dlo * VTSTR + (m0c + mtl * 16 + quad * 4 + i)] = f2h(acc[i] + bval);
      } else {               // Q -> Qs[ql*16+row][d]
        int ql = gt - qt0;
#pragma unroll
        for (int i = 0; i < 4; ++i)
          Qs[(ql * 16 + quad * 4 + i) * QSTR + dlo] = f2h(acc[i] + bval);
      }
    }
  }
  __syncthreads();   // Ks/Vt/Qs complete; Wl/Ach dead -> Ps may overlay

  // ---- phase 2: flash attention (R3 structure) ----
  _Float16* P = PsB + wave * (16 * PSTR);
  const f16x8 onesv = {(_Float16)1.f, (_Float16)1.f, (_Float16)1.f, (_Float16)1.f,
                       (_Float16)1.f, (_Float16)1.f, (_Float16)1.f, (_Float16)1.f};

  for (int qtile = qt0 + wave; qtile < qtend; qtile += 8) {
    int qb = qtile * 16;
    int ql = qtile - qt0;

    f16x8 qf = *(const f16x8*)&Qs[(ql * 16 + lcol) * QSTR + quad * 8];
    f32x4 accA = {0.f, 0.f, 0.f, 0.f};
    f32x4 accB = {0.f, 0.f, 0.f, 0.f};
    f32x4 lacc = {0.f, 0.f, 0.f, 0.f};
    float m_[4] = {-1e30f, -1e30f, -1e30f, -1e30f};

    // 336 = 5*64 + 16: T=0..4 full 64-key blocks, T=5 tail (16 keys)
    for (int T = 0; T < 6; ++T) {
      int k0 = T * 64;
      bool full = (T < 5);
      f32x4 s[4];
      {
        const _Float16* kp = &Ks[(k0 + lcol) * KSTR + quad * 8];
        f16x4v a0 = *(const f16x4v*)kp;
        f16x4v b0 = *(const f16x4v*)(kp + 4);
        f16x8 kf = __builtin_shufflevector(a0, b0, 0, 1, 2, 3, 4, 5, 6, 7);
        s[0] = __builtin_amdgcn_mfma_f32_16x16x32_f16(qf, kf, z4, 0, 0, 0);
      }
      if (full) {
#pragma unroll
        for (int u = 1; u < 4; ++u) {
          const _Float16* kp = &Ks[(k0 + u * 16 + lcol) * KSTR + quad * 8];
          f16x4v a0 = *(const f16x4v*)kp;
          f16x4v b0 = *(const f16x4v*)(kp + 4);
          f16x8 kf = __builtin_shufflevector(a0, b0, 0, 1, 2, 3, 4, 5, 6, 7);
          s[u] = __builtin_amdgcn_mfma_f32_16x16x32_f16(qf, kf, z4, 0, 0, 0);
        }
      } else {
        s[1] = z4; s[2] = z4; s[3] = z4;
      }
      float sc[4][4], p[4][4], corr[4];
#pragma unroll
      for (int u = 0; u < 4; ++u)
#pragma unroll
        for (int i = 0; i < 4; ++i)
          sc[u][i] = (u == 0 || full) ? s[u][i] * ATT_SCALE : -1e30f;
#pragma unroll
      for (int i = 0; i < 4; ++i) {
        float t2 = fmaxf(fmaxf(sc[0][i], sc[1][i]), fmaxf(sc[2][i], sc[3][i]));
        t2 = fmaxf(t2, __shfl_xor(t2, 1));
        t2 = fmaxf(t2, __shfl_xor(t2, 2));
        t2 = fmaxf(t2, __shfl_xor(t2, 4));
        t2 = fmaxf(t2, __shfl_xor(t2, 8));
        float nm = fmaxf(m_[i], t2);
        corr[i] = __expf(m_[i] - nm);
        m_[i] = nm;
#pragma unroll
        for (int u = 0; u < 4; ++u) p[u][i] = __expf(sc[u][i] - nm);
        accA[i] *= corr[i];
        accB[i] *= corr[i];
        lacc[i] *= corr[i];
      }
#pragma unroll
      for (int i = 0; i < 4; ++i)
#pragma unroll
        for (int u = 0; u < 4; ++u)
          P[(quad * 4 + i) * PSTR + u * 16 + lcol] = f2h(p[u][i]);
      f16x8 pf0 = *(const f16x8*)&P[lcol * PSTR + quad * 8];
      lacc = __builtin_amdgcn_mfma_f32_16x16x32_f16(pf0, onesv, lacc, 0, 0, 0);
      f16x8 va0 = *(const f16x8*)&Vt[lcol * VTSTR + k0 + quad * 8];
      f16x8 vb0 = *(const f16x8*)&Vt[(16 + lcol) * VTSTR + k0 + quad * 8];
      accA = __builtin_amdgcn_mfma_f32_16x16x32_f16(pf0, va0, accA, 0, 0, 0);
      accB = __builtin_amdgcn_mfma_f32_16x16x32_f16(pf0, vb0, accB, 0, 0, 0);
      if (full) {
        f16x8 pf1 = *(const f16x8*)&P[lcol * PSTR + 32 + quad * 8];
        lacc = __builtin_amdgcn_mfma_f32_16x16x32_f16(pf1, onesv, lacc, 0, 0, 0);
        f16x8 va1 = *(const f16x8*)&Vt[lcol * VTSTR + k0 + 32 + quad * 8];
        f16x8 vb1 = *(const f16x8*)&Vt[(16 + lcol) * VTSTR + k0 + 32 + quad * 8];
        accA = __builtin_amdgcn_mfma_f32_16x16x32_f16(pf1, va1, accA, 0, 0, 0);
        accB = __builtin_amdgcn_mfma_f32_16x16x32_f16(pf1, vb1, accB, 0, 0, 0);
      }
    }

#pragma unroll
    for (int i = 0; i < 4; ++i) {
      float inv = 1.f / lacc[i];
      P[(quad * 4 + i) * PSTR + lcol] = f2h(accA[i] * inv);
      P[(quad * 4 + i) * PSTR + 16 + lcol] = f2h(accB[i] * inv);
    }
    int row = lane >> 2, seg = lane & 3;
    f16x8 ov = *(const f16x8*)&P[row * PSTR + seg * 8];
    *(f16x8*)&O16[base + (size_t)(qb + row) * DD + seg * 8] = ov;
  }
}

// ---------------- MEGA var stage (32 rows/block, 8 waves) -------------------
// grid 168 x 512thr; time O-proj + 2xLN + var QKV + var attn + var O-proj +
// final LN. nextQKV moved into k_attn_time; handoff is Et16 (f16 of final LN).
__global__ __launch_bounds__(512) void k_mega_var(
    const _Float16* __restrict__ AO16, const _Float16* __restrict__ WT2,
    const float* __restrict__ bq, const float* __restrict__ bk,
    const float* __restrict__ bv, const float* __restrict__ bo,
    const float* __restrict__ g1, const float* __restrict__ c1,
    const float* __restrict__ gn, const float* __restrict__ bn,
    float* __restrict__ Etime, _Float16* __restrict__ Et16) {
  int tid = threadIdx.x;
  int wave = tid >> 6, lane = tid & 63;
  int quad = lane >> 4, lcol = lane & 15;

  __shared__ int rmapS[32];
  __shared__ _Float16 Af[32 * 264];    // 16.5 KB
  __shared__ float Cf[32 * 260];       // 33.3 KB
  __shared__ _Float16 QKVs[32 * 776];  // 48.5 KB

  if (tid < 32) {
    int r2 = blockIdx.x * 32 + tid;
    int n_idx = r2 >> 3, v = r2 & 7;
    int b = n_idx / SS, s = n_idx - b * SS;
    rmapS[tid] = (b * VV + v) * SS + s;
  }
  __syncthreads();

  // stage AO rows (time layout, gathered) into Af
  {
    int row = tid >> 4, seg = tid & 15;
    const _Float16* src = AO16 + (size_t)rmapS[row] * DD + seg * 16;
    _Float16* dst = Af + row * 264 + seg * 16;
    *(f16x8*)(dst) = *(const f16x8*)(src);
    *(f16x8*)(dst + 8) = *(const f16x8*)(src + 8);
  }
  __syncthreads();

  const _Float16* WoF = WT2 + (size_t)3 * 65536;   // Wo frag block

  // ---- time O-proj: Cf = Af @ Wo + bo + Etime(res) ----
  {
    f32x4 acc[2][2] = {};
    for (int kb = 0; kb < 8; ++kb) {
      int k0 = kb * 32;
      f16x8 af0 = *(const f16x8*)&Af[lcol * 264 + k0 + quad * 8];
      f16x8 af1 = *(const f16x8*)&Af[(16 + lcol) * 264 + k0 + quad * 8];
#pragma unroll
      for (int nt = 0; nt < 2; ++nt) {
        f16x8 bfr = *(const f16x8*)&WoF[((wave * 2 + nt) * 8 + kb) * 512 + lane * 8];
        acc[0][nt] = __builtin_amdgcn_mfma_f32_16x16x32_f16(af0, bfr, acc[0][nt], 0, 0, 0);
        acc[1][nt] = __builtin_amdgcn_mfma_f32_16x16x32_f16(af1, bfr, acc[1][nt], 0, 0, 0);
      }
    }
#pragma unroll
    for (int mt = 0; mt < 2; ++mt) {
#pragma unroll
      for (int i = 0; i < 4; ++i) {
        int row = mt * 16 + quad * 4 + i;
        size_t rb = (size_t)rmapS[row] * 256;
#pragma unroll
        for (int nt = 0; nt < 2; ++nt) {
          int col = (wave * 2 + nt) * 16 + lcol;
          Cf[row * 260 + col] = acc[mt][nt][i] + bo[col] + Etime[rb + col];
        }
      }
    }
  }
  __syncthreads();

  // ---- double LN (ln1 then norm); write Cf fp32 + Af f16 ----
  {
    int row = tid >> 4, c0 = (tid & 15) * 16;
    float v[16];
#pragma unroll
    for (int j = 0; j < 16; ++j) v[j] = Cf[row * 260 + c0 + j];
#pragma unroll
    for (int pass = 0; pass < 2; ++pass) {
      const float* gg = pass ? gn : g1;
      const float* bb = pass ? bn : c1;
      float s = 0.f, q = 0.f;
#pragma unroll
      for (int j = 0; j < 16; ++j) { s += v[j]; q = fmaf(v[j], v[j], q); }
      s += __shfl_xor(s, 1); q += __shfl_xor(q, 1);
      s += __shfl_xor(s, 2); q += __shfl_xor(q, 2);
      s += __shfl_xor(s, 4); q += __shfl_xor(q, 4);
      s += __shfl_xor(s, 8); q += __shfl_xor(q, 8);
      float mu = s * (1.0f / 256.0f);
      float rs = rsqrtf(q * (1.0f / 256.0f) - mu * mu + LN_EPS);
#pragma unroll
      for (int j = 0; j < 16; ++j)
        v[j] = fmaf((v[j] - mu) * rs, gg[c0 + j], bb[c0 + j]);
    }
#pragma unroll
    for (int j = 0; j < 16; ++j) Cf[row * 260 + c0 + j] = v[j];
#pragma unroll
    for (int j8 = 0; j8 < 2; ++j8) {
      f16x8 h;
#pragma unroll
      for (int jj = 0; jj < 8; ++jj) h[jj] = f2h(v[j8 * 8 + jj]);
      *(f16x8*)&Af[row * 264 + c0 + j8 * 8] = h;
    }
  }
  __syncthreads();

  // ---- var QKV: QKVs[32][768] = Af @ {Wq|Wk|Wv} + bias ----
  {
    f32x4 acc[2][6] = {};
    for (int kb = 0; kb < 8; ++kb) {
      int k0 = kb * 32;
      f16x8 af0 = *(const f16x8*)&Af[lcol * 264 + k0 + quad * 8];
      f16x8 af1 = *(const f16x8*)&Af[(16 + lcol) * 264 + k0 + quad * 8];
#pragma unroll
      for (int j = 0; j < 6; ++j) {
        int ntg = wave * 6 + j;                   // 0..47 == z*16 + ntile
        f16x8 bfr = *(const f16x8*)&WT2[(size_t)(ntg * 8 + kb) * 512 + lane * 8];
        acc[0][j] = __builtin_amdgcn_mfma_f32_16x16x32_f16(af0, bfr, acc[0][j], 0, 0, 0);
        acc[1][j] = __builtin_amdgcn_mfma_f32_16x16x32_f16(af1, bfr, acc[1][j], 0, 0, 0);
      }
    }
#pragma unroll
    for (int j = 0; j < 6; ++j) {
      int ntg = wave * 6 + j;
      int colb = ntg * 16;
      int z = colb >> 8, coln = (colb & 255) + lcol;
      const float* bz = (z == 0) ? bq : (z == 1) ? bk : bv;
      float bval = bz[coln];
#pragma unroll
      for (int mt = 0; mt < 2; ++mt) {
#pragma unroll
        for (int i = 0; i < 4; ++i)
          QKVs[(mt * 16 + quad * 4 + i) * 776 + colb + lcol] = f2h(acc[mt][j][i] + bval);
      }
    }
  }
  __syncthreads();

  // ---- var attention: all 512 thr; thread pairs split the 32 dims ----
  {
    int half = tid & 1, qi = (tid >> 1) & 7, h = (tid >> 4) & 7, ng = tid >> 7;
    int d0 = h * 32 + half * 16;
    const _Float16* Qp = &QKVs[(ng * 8 + qi) * 776 + d0];
    float qv[16];
#pragma unroll
    for (int j8 = 0; j8 < 2; ++j8) {
      f16x8 t = *(const f16x8*)(Qp + j8 * 8);
#pragma unroll
      for (int jj = 0; jj < 8; ++jj) qv[j8 * 8 + jj] = (float)t[jj];
    }
    float sc[8];
#pragma unroll
    for (int k = 0; k < 8; ++k) {
      const _Float16* Kp = &QKVs[(ng * 8 + k) * 776 + 256 + d0];
      float s = 0.f;
#pragma unroll
      for (int j8 = 0; j8 < 2; ++j8) {
        f16x8 t = *(const f16x8*)(Kp + j8 * 8);
#pragma unroll
        for (int jj = 0; jj < 8; ++jj) s = fmaf(qv[j8 * 8 + jj], (float)t[jj], s);
      }
      sc[k] = s;
    }
#pragma unroll
    for (int k = 0; k < 8; ++k)
      sc[k] = (sc[k] + __shfl_xor(sc[k], 1)) * ATT_SCALE;
    float mx = sc[0];
#pragma unroll
    for (int k = 1; k < 8; ++k) mx = fmaxf(mx, sc[k]);
    float ps = 0.f;
#pragma unroll
    for (int k = 0; k < 8; ++k) { sc[k] = __expf(sc[k] - mx); ps += sc[k]; }
    float inv = 1.f / ps;
    float ov[16];
#pragma unroll
    for (int j = 0; j < 16; ++j) ov[j] = 0.f;
#pragma unroll
    for (int k = 0; k < 8; ++k) {
      const _Float16* Vp = &QKVs[(ng * 8 + k) * 776 + 512 + d0];
      float p = sc[k];
#pragma unroll
      for (int j8 = 0; j8 < 2; ++j8) {
        f16x8 t = *(const f16x8*)(Vp + j8 * 8);
#pragma unroll
        for (int jj = 0; jj < 8; ++jj)
          ov[j8 * 8 + jj] = fmaf(p, (float)t[jj], ov[j8 * 8 + jj]);
      }
    }
    _Float16* Op = &Af[(ng * 8 + qi) * 264 + d0];
#pragma unroll
    for (int j8 = 0; j8 < 2; ++j8) {
      f16x8 hh;
#pragma unroll
      for (int jj = 0; jj < 8; ++jj) hh[jj] = f2h(ov[j8 * 8 + jj] * inv);
      *(f16x8*)(Op + j8 * 8) = hh;
    }
  }
  __syncthreads();

  // ---- var O-proj: Cf = Af @ Wo + bo + Cf(res x_var) ----
  {
    f32x4 acc[2][2] = {};
    for (int kb = 0; kb < 8; ++kb) {
      int k0 = kb * 32;
      f16x8 af0 = *(const f16x8*)&Af[lcol * 264 + k0 + quad * 8];
      f16x8 af1 = *(const f16x8*)&Af[(16 + lcol) * 264 + k0 + quad * 8];
#pragma unroll
      for (int nt = 0; nt < 2; ++nt) {
        f16x8 bfr = *(const f16x8*)&WoF[((wave * 2 + nt) * 8 + kb) * 512 + lane * 8];
        acc[0][nt] = __builtin_amdgcn_mfma_f32_16x16x32_f16(af0, bfr, acc[0][nt], 0, 0, 0);
        acc[1][nt] = __builtin_amdgcn_mfma_f32_16x16x32_f16(af1, bfr, acc[1][nt], 0, 0, 0);
      }
    }
#pragma unroll
    for (int mt = 0; mt < 2; ++mt) {
#pragma unroll
      for (int i = 0; i < 4; ++i) {
        int row = mt * 16 + quad * 4 + i;
#pragma unroll
        for (int nt = 0; nt < 2; ++nt) {
          int col = (wave * 2 + nt) * 16 + lcol;
          Cf[row * 260 + col] = acc[mt][nt][i] + bo[col] + Cf[row * 260 + col];
        }
      }
    }
  }
  __syncthreads();

  // ---- final LN1 + store Etime (f32) + Et16 (f16 handoff to attn QKV) ----
  {
    int row = tid >> 4, c0 = (tid & 15) * 16;
    float v[16];
#pragma unroll
    for (int j = 0; j < 16; ++j) v[j] = Cf[row * 260 + c0 + j];
    float s = 0.f, q = 0.f;
#pragma unroll
    for (int j = 0; j < 16; ++j) { s += v[j]; q = fmaf(v[j], v[j], q); }
    s += __shfl_xor(s, 1); q += __shfl_xor(q, 1);
    s += __shfl_xor(s, 2); q += __shfl_xor(q, 2);
    s += __shfl_xor(s, 4); q += __shfl_xor(q, 4);
    s += __shfl_xor(s, 8); q += __shfl_xor(q, 8);
    float mu = s * (1.0f / 256.0f);
    float rs = rsqrtf(q * (1.0f / 256.0f) - mu * mu + LN_EPS);
#pragma unroll
    for (int j = 0; j < 16; ++j)
      v[j] = fmaf((v[j] - mu) * rs, g1[c0 + j], c1[c0 + j]);
    size_t rb = (size_t)rmapS[row] * 256 + c0;
#pragma unroll
    for (int j4 = 0; j4 < 4; ++j4) {
      float4 f4 = make_float4(v[j4 * 4], v[j4 * 4 + 1], v[j4 * 4 + 2], v[j4 * 4 + 3]);
      *(float4*)&Etime[rb + j4 * 4] = f4;
    }
#pragma unroll
    for (int j8 = 0; j8 < 2; ++j8) {
      f16x8 hh;
#pragma unroll
      for (int jj = 0; jj < 8; ++jj) hh[jj] = f2h(v[j8 * 8 + jj]);
      *(f16x8*)&Et16[rb + j8 * 8] = hh;
    }
  }
}

// ---------------- final projection -----------------------------------------
__global__ __launch_bounds__(192) void k_proj_partial(
    const float* __restrict__ E, const float* __restrict__ PW,
    float* __restrict__ Part) {
  int kc = blockIdx.x;
  int tid = threadIdx.x;
  int p4 = tid % 24, g = tid / 24;
  __shared__ float Es[16][128];
  __shared__ float sm[8][1536];
  for (int idx = tid; idx < 512; idx += 192) {
    int row = idx >> 5, kk4 = idx & 31;
    *(float4*)&Es[row][kk4 * 4] =
        *(const float4*)&E[(size_t)row * 86016 + kc * 128 + kk4 * 4];
  }
  __syncthreads();
  float4 acc[16];
#pragma unroll
  for (int i = 0; i < 16; ++i) acc[i] = make_float4(0.f, 0.f, 0.f, 0.f);
  for (int j = 0; j < 16; ++j) {
    int k = g * 16 + j;
    float4 w = *(const float4*)&PW[(size_t)(kc * 128 + k) * 96 + p4 * 4];
#pragma unroll
    for (int row = 0; row < 16; ++row) {
      float e = Es[row][k];
      acc[row].x = fmaf(e, w.x, acc[row].x);
      acc[row].y = fmaf(e, w.y, acc[row].y);
      acc[row].z = fmaf(e, w.z, acc[row].z);
      acc[row].w = fmaf(e, w.w, acc[row].w);
    }
  }
#pragma unroll
  for (int row = 0; row < 16; ++row)
    *(float4*)&sm[g][row * 96 + p4 * 4] = acc[row];
  __syncthreads();
  for (int o = tid; o < 1536; o += 192) {
    float s = 0.f;
#pragma unroll
    for (int g2 = 0; g2 < 8; ++g2) s += sm[g2][o];
    Part[(size_t)kc * 1536 + o] = s;
  }
}

// 96 blocks x 256 thr: block owns 16 j's; 16-way c-split per j, tree-reduce.
__global__ __launch_bounds__(256) void k_proj_reduce(
    const float* __restrict__ Part, const float* __restrict__ PB,
    float* __restrict__ out) {
  __shared__ float red[4][16];
  int tid = threadIdx.x;
  int j = (blockIdx.x << 4) | (tid & 15);   // 0..1535
  int cg = tid >> 4;                         // 0..15
  float s = 0.f;
#pragma unroll 7
  for (int i = 0; i < 42; ++i) {
    int c = cg * 42 + i;
    s += Part[(size_t)c * 1536 + j];
  }
  s += __shfl_xor(s, 16);
  s += __shfl_xor(s, 32);
  int wv = tid >> 6;
  if ((tid & 63) < 16) red[wv][tid & 15] = s;
  __syncthreads();
  if (tid < 16) {
    float t = red[0][tid] + red[1][tid] + red[2][tid] + red[3][tid];
    int jj = (blockIdx.x << 4) | tid;
    int row = jj / 96, p = jj - row * 96;
    int b = row >> 3, v = row & 7;
    out[b * 768 + p * 8 + v] = PB[p] + t;
  }
}

// ---------------- launch ---------------------------------------------------
extern "C" void kernel_launch(void* const* d_in, const int* in_sizes, int n_in,
                              void* d_out, int out_size, void* d_ws,
                              size_t ws_size, hipStream_t stream) {
  const float* x     = (const float*)d_in[0];
  const float* emb_w = (const float*)d_in[1];
  const float* emb_b = (const float*)d_in[2];
  const float* Wq = (const float*)d_in[3];
  const float* bq = (const float*)d_in[4];
  const float* Wk = (const float*)d_in[5];
  const float* bk = (const float*)d_in[6];
  const float* Wv = (const float*)d_in[7];
  const float* bv = (const float*)d_in[8];
  const float* Wo = (const float*)d_in[9];
  const float* bo = (const float*)d_in[10];
  const float* g1 = (const float*)d_in[11];
  const float* b1 = (const float*)d_in[12];
  const float* gn = (const float*)d_in[13];
  const float* bn = (const float*)d_in[14];
  const float* PW = (const float*)d_in[15];
  const float* PB = (const float*)d_in[16];
  float* out = (float*)d_out;

  float* ws = (float*)d_ws;
  float* Etime   = ws;                              // NTD f32
  _Float16* Et16 = (_Float16*)(ws + (size_t)NTD);   // NTD f16
  _Float16* AO16 = Et16 + (size_t)NTD;              // NTD f16
  _Float16* WT2  = AO16 + (size_t)NTD;              // 4*65536 f16 (frag order)
  float* Part    = (float*)(WT2 + 4 * 65536);       // 672*1536 f32

  k_prep_w<<<dim3(256, 4), 256, 0, stream>>>(Wq, Wk, Wv, Wo, WT2);
  k_embed<<<NTOK, 256, 0, stream>>>(x, emb_w, emb_b, Etime, Et16);
  for (int it = 0; it < 10; ++it) {
    k_attn_time<<<dim3(2, 8, 16), 512, 0, stream>>>(
        Et16, WT2, bq, bk, bv, AO16);
    k_mega_var<<<168, 512, 0, stream>>>(
        AO16, WT2, bq, bk, bv, bo, g1, b1, gn, bn, Etime, Et16);
  }
  k_proj_partial<<<672, 192, 0, stream>>>(Etime, PW, Part);
  k_proj_reduce<<<96, 256, 0, stream>>>(Part, PB, out);
}